// Round 6
// baseline (457.214 us; speedup 1.0000x reference)
//
#include <hip/hip_runtime.h>

// Problem constants (fixed by the reference)
#define N_NODES 100000
#define N_EDGES 1600000
#define DIM     128
#define EDIM    16
#define NLAYERS 5

typedef unsigned short ushort_t;
typedef short bf16x8 __attribute__((ext_vector_type(8)));   // 8 bf16 in 4 VGPRs
typedef float f32x4  __attribute__((ext_vector_type(4)));

__device__ __forceinline__ ushort_t f2bf(float f) {
    union { float f; unsigned int i; } c; c.f = f;
    unsigned int r = c.i + 0x7fffu + ((c.i >> 16) & 1u);   // RNE
    return (ushort_t)(r >> 16);
}
__device__ __forceinline__ float lo_bf(unsigned int w) {
    union { unsigned int i; float f; } c; c.i = w << 16; return c.f;
}
__device__ __forceinline__ float hi_bf(unsigned int w) {
    union { unsigned int i; float f; } c; c.i = w & 0xffff0000u; return c.f;
}
__device__ __forceinline__ unsigned int pk_bf16(float lo, float hi) {
    unsigned int r;
    asm("v_cvt_pk_bf16_f32 %0, %1, %2" : "=v"(r) : "v"(lo), "v"(hi));
    return r;
}
__device__ __forceinline__ bf16x8 pk8(f32x4 a, f32x4 b) {
    union { unsigned int w[4]; bf16x8 v; } c;
    c.w[0] = pk_bf16(a[0], a[1]); c.w[1] = pk_bf16(a[2], a[3]);
    c.w[2] = pk_bf16(b[0], b[1]); c.w[3] = pk_bf16(b[2], b[3]);
    return c.v;
}

// ---------------------------------------------------------------------------
// Swizzle eW1 (272x16) / eW2 (16x16) per layer (fp32) into bf16 B-fragments.
// B[k][n]: lane = 16*quad + n holds k = quad*8 + j.
// NOTE: the B-fragment of M is bit-identical to the A-fragment of M^T, so
// these same buffers serve the transposed (operand-swapped) MFMAs below.
// w1s: [layer][t(0..8)][lane][8]; t0..3 = W1a (k 0..127, s_src block),
//      t4..7 = W1b (k 128..255, s_dst), t8 = W1c (k 256..271, ea; zero-pad).
// w2s: [layer][lane][8]; K padded 16->32 (ZEROS at k>=16 -- relied upon by
// the shfl-transpose in edge_fused: garbage B rows at k>=16 multiply by 0).
// ---------------------------------------------------------------------------
__global__ void swizzle_weights(const float* __restrict__ eW1,
                                const float* __restrict__ eW2,
                                ushort_t* __restrict__ w1s,
                                ushort_t* __restrict__ w2s) {
    int id = blockIdx.x * 256 + threadIdx.x;
    if (id >= NLAYERS * 10 * 64) return;
    int lane = id & 63;
    int t10 = id >> 6;
    int layer = t10 / 10, t = t10 % 10;
    int n = lane & 15, quad = lane >> 4;
    if (t < 9) {
        ushort_t* dst = w1s + ((size_t)(layer * 9 + t) * 64 + lane) * 8;
        #pragma unroll
        for (int j = 0; j < 8; ++j) {
            int k = t * 32 + quad * 8 + j;
            dst[j] = (k < 2 * DIM + EDIM)
                       ? f2bf(eW1[((size_t)layer * 272 + k) * 16 + n])
                       : (ushort_t)0;
        }
    } else {
        ushort_t* dst = w2s + ((size_t)layer * 64 + lane) * 8;
        #pragma unroll
        for (int j = 0; j < 8; ++j) {
            int k = quad * 8 + j;
            dst[j] = (k < EDIM) ? f2bf(eW2[((size_t)layer * 16 + k) * 16 + n])
                                : (ushort_t)0;
        }
    }
}

// ---------------------------------------------------------------------------
// Fused LayerNorm chain + per-node projections. One wave per 16 nodes; each
// node's 128-float row lives in registers across layers l0..l1-1:
//   for each layer: s = LN(s);  u_l = s @ W1a_l;  v_l = s @ W1b_l  (bf16 out)
// MFMA operands are SWAPPED (D = W^T . s^T): lane(quad,m) then holds
// u[node tile*16+m][features quad*4+0..3], which packs into ONE 8B store
// into the edge-kernel-friendly layout u_buf[node][lstr][16].
// ---------------------------------------------------------------------------
__global__ __launch_bounds__(256) void ln_uv(
        const float* __restrict__ sin, float* __restrict__ sout,
        const float* __restrict__ lnw, const float* __restrict__ lnb, // [5][128]
        const ushort_t* __restrict__ w1s,                             // all layers
        ushort_t* __restrict__ u_buf, ushort_t* __restrict__ v_buf,
        int l0, int l1, int lstr) {
    const int wv = threadIdx.x >> 6, lane = threadIdx.x & 63;
    const int m = lane & 15, quad = lane >> 4;
    const int tile = blockIdx.x * 4 + wv;
    if (tile >= N_NODES / 16) return;           // 6250 tiles exactly
    const int node = tile * 16 + m;

    float x[32];
    {
        const float* row = sin + (size_t)node * DIM + quad * 8;
        #pragma unroll
        for (int t = 0; t < 4; ++t) {
            f32x4 a = *(const f32x4*)(row + t * 32);
            f32x4 b = *(const f32x4*)(row + t * 32 + 4);
            #pragma unroll
            for (int j = 0; j < 4; ++j) { x[t * 8 + j] = a[j]; x[t * 8 + 4 + j] = b[j]; }
        }
    }

    for (int li = l0; li < l1; ++li) {
        // --- LayerNorm (fp32, row spread across the 4 quads of lanes w/ same m)
        float s = 0.f;
        #pragma unroll
        for (int k = 0; k < 32; ++k) s += x[k];
        s += __shfl_xor(s, 16); s += __shfl_xor(s, 32);
        float mu = s * (1.0f / DIM);
        float ss = 0.f;
        #pragma unroll
        for (int k = 0; k < 32; ++k) { float d = x[k] - mu; ss += d * d; }
        ss += __shfl_xor(ss, 16); ss += __shfl_xor(ss, 32);
        float rs = rsqrtf(ss * (1.0f / DIM) + 1e-5f);

        const float* w = lnw + (size_t)li * DIM + quad * 8;
        const float* b = lnb + (size_t)li * DIM + quad * 8;
        f32x4 au = {0.f, 0.f, 0.f, 0.f}, av = {0.f, 0.f, 0.f, 0.f};
        #pragma unroll
        for (int t = 0; t < 4; ++t) {
            f32x4 wa = *(const f32x4*)(w + t * 32), wb = *(const f32x4*)(w + t * 32 + 4);
            f32x4 ba = *(const f32x4*)(b + t * 32), bb = *(const f32x4*)(b + t * 32 + 4);
            #pragma unroll
            for (int j = 0; j < 4; ++j) {
                x[t * 8 + j]     = (x[t * 8 + j]     - mu) * rs * wa[j] + ba[j];
                x[t * 8 + 4 + j] = (x[t * 8 + 4 + j] - mu) * rs * wb[j] + bb[j];
            }
            f32x4 ya, yb;
            #pragma unroll
            for (int j = 0; j < 4; ++j) { ya[j] = x[t * 8 + j]; yb[j] = x[t * 8 + 4 + j]; }
            bf16x8 af = pk8(ya, yb);
            bf16x8 bu = *(const bf16x8*)(w1s + ((size_t)(li * 9 + t)     * 64 + lane) * 8);
            bf16x8 bv = *(const bf16x8*)(w1s + ((size_t)(li * 9 + 4 + t) * 64 + lane) * 8);
            // swapped operands: D = W^T . s^T  (weight B-frag == A-frag of W^T)
            au = __builtin_amdgcn_mfma_f32_16x16x32_bf16(bu, af, au, 0, 0, 0);
            av = __builtin_amdgcn_mfma_f32_16x16x32_bf16(bv, af, av, 0, 0, 0);
        }
        // D layout (transposed): lane(quad,m) = u[node m][feature quad*4+r]
        size_t rec = ((size_t)node * lstr + (li - l0)) * EDIM + quad * 4;
        uint2 tu; tu.x = pk_bf16(au[0], au[1]); tu.y = pk_bf16(au[2], au[3]);
        uint2 tv; tv.x = pk_bf16(av[0], av[1]); tv.y = pk_bf16(av[2], av[3]);
        *(uint2*)(u_buf + rec) = tu;
        *(uint2*)(v_buf + rec) = tv;
    }

    float* orow = sout + (size_t)node * DIM + quad * 8;
    #pragma unroll
    for (int t = 0; t < 4; ++t) {
        f32x4 a, b;
        #pragma unroll
        for (int j = 0; j < 4; ++j) { a[j] = x[t * 8 + j]; b[j] = x[t * 8 + 4 + j]; }
        *(f32x4*)(orow + t * 32) = a;
        *(f32x4*)(orow + t * 32 + 4) = b;
    }
}

// ---------------------------------------------------------------------------
// FUSED edge pass: all NL layers in registers, ea read/written from global
// ONCE. Transposed orientation: per 16-edge wave-tile, lane(quad,m) owns
// edge column m, feature rows quad*4+r.
//   h1^T  = W1c^T . ea^T   (A = existing w1c B-frag, B = ea^T frag)
//   ea'^T = W2^T  . h1^T
// u/v gathers: ONE 8B load per lane per layer from u_buf[node][NL][16]
// (prefetched for all layers up-front; node record = 160B contiguous).
//
// C-layout -> B-frag transpose is a fixed 16-lane-stride exchange, done with
// 4 __shfl (ds_bpermute): lane(quad',m) takes packed pairs from lanes
// srcA = m + (quad'&1)*32 and srcB = srcA+16.  Quads 2,3 receive finite
// duplicates of quads 0,1 -- annihilated by the ZERO rows (k>=16) of the
// W2 / W1c-pad weight fragments, so no masking is needed.  No LDS, no
// fences, no bank conflicts.
// In-place safe: each edge is read and written entirely by its own wave,
// reads precede writes through register dependencies.
// ---------------------------------------------------------------------------
template<int NL>
__global__ __launch_bounds__(256) void edge_fused(
        const float* __restrict__ ea_in, float* __restrict__ ea_out,
        const int* __restrict__ ei,
        const ushort_t* __restrict__ u_buf, const ushort_t* __restrict__ v_buf,
        const ushort_t* __restrict__ w1s, const ushort_t* __restrict__ w2s,
        const float* __restrict__ eb1, const float* __restrict__ eb2,
        int l0) {
    const int wv = threadIdx.x >> 6, lane = threadIdx.x & 63;
    const int m = lane & 15, quad = lane >> 4;

    bf16x8 w1f[NL], w2f[NL];
    f32x4 b1[NL], b2[NL];
    #pragma unroll
    for (int l = 0; l < NL; ++l) {
        w1f[l] = *(const bf16x8*)(w1s + (((size_t)(l0 + l) * 9 + 8) * 64 + lane) * 8);
        w2f[l] = *(const bf16x8*)(w2s + ((size_t)(l0 + l) * 64 + lane) * 8);
        #pragma unroll
        for (int r = 0; r < 4; ++r) {
            b1[l][r] = eb1[(l0 + l) * EDIM + quad * 4 + r];
            b2[l][r] = eb2[(l0 + l) * EDIM + quad * 4 + r];
        }
    }
    const bf16x8 zf = {0, 0, 0, 0, 0, 0, 0, 0};
    const int nTiles = N_EDGES / 64;
    // transpose sources (wave-constant per lane)
    const int srcA = m + ((quad & 1) << 5);
    const int srcB = srcA + 16;

    for (int tile = blockIdx.x; tile < nTiles; tile += gridDim.x) {
        const int e = tile * 64 + wv * 16 + m;     // this lane's edge column
        const int es = ei[e];
        const int ed = ei[N_EDGES + e];

        // Prefetch ALL layers' u/v slices: 8B contiguous per lane per layer.
        uint2 gu[NL], gv[NL];
        #pragma unroll
        for (int l = 0; l < NL; ++l) {
            gu[l] = *(const uint2*)(u_buf + ((size_t)es * NL + l) * EDIM + quad * 4);
            gv[l] = *(const uint2*)(v_buf + ((size_t)ed * NL + l) * EDIM + quad * 4);
        }

        // ea^T B-frag: lane(quad<2,m) = ea[edge m][quad*8 .. +7]
        bf16x8 af = zf;
        if (quad < 2) {
            const float* ep = ea_in + (size_t)e * EDIM + quad * 8;
            af = pk8(*(const f32x4*)ep, *(const f32x4*)(ep + 4));
        }

        f32x4 y = {0.f, 0.f, 0.f, 0.f};
        #pragma unroll
        for (int l = 0; l < NL; ++l) {
            f32x4 acc = {0.f, 0.f, 0.f, 0.f};
            acc = __builtin_amdgcn_mfma_f32_16x16x32_bf16(w1f[l], af, acc, 0, 0, 0);
            // acc[r] = (ea@W1c)[edge m][feature 4q+r]; add u[src],v[dst],bias; silu
            float x0 = acc[0] + lo_bf(gu[l].x) + lo_bf(gv[l].x) + b1[l][0];
            float x1 = acc[1] + hi_bf(gu[l].x) + hi_bf(gv[l].x) + b1[l][1];
            float x2 = acc[2] + lo_bf(gu[l].y) + lo_bf(gv[l].y) + b1[l][2];
            float x3 = acc[3] + hi_bf(gu[l].y) + hi_bf(gv[l].y) + b1[l][3];
            float h0 = x0 / (1.0f + __expf(-x0));
            float h1 = x1 / (1.0f + __expf(-x1));
            float h2 = x2 / (1.0f + __expf(-x2));
            float h3 = x3 / (1.0f + __expf(-x3));

            // transpose h^T (C layout) -> B-frag via 4 shfl, no LDS
            unsigned int hx = pk_bf16(h0, h1), hy = pk_bf16(h2, h3);
            union { unsigned int w[4]; bf16x8 v; } hc;
            hc.w[0] = (unsigned int)__shfl((int)hx, srcA);
            hc.w[1] = (unsigned int)__shfl((int)hy, srcA);
            hc.w[2] = (unsigned int)__shfl((int)hx, srcB);
            hc.w[3] = (unsigned int)__shfl((int)hy, srcB);

            f32x4 acc2 = {0.f, 0.f, 0.f, 0.f};
            acc2 = __builtin_amdgcn_mfma_f32_16x16x32_bf16(w2f[l], hc.v, acc2, 0, 0, 0);
            y[0] = acc2[0] + b2[l][0];
            y[1] = acc2[1] + b2[l][1];
            y[2] = acc2[2] + b2[l][2];
            y[3] = acc2[3] + b2[l][3];

            if (l < NL - 1) {
                unsigned int yx = pk_bf16(y[0], y[1]), yy = pk_bf16(y[2], y[3]);
                union { unsigned int w[4]; bf16x8 v; } yc;
                yc.w[0] = (unsigned int)__shfl((int)yx, srcA);
                yc.w[1] = (unsigned int)__shfl((int)yy, srcA);
                yc.w[2] = (unsigned int)__shfl((int)yx, srcB);
                yc.w[3] = (unsigned int)__shfl((int)yy, srcB);
                af = yc.v;
            }
        }
        // store ea'[edge m][4q..4q+3] : contiguous 16B per lane
        *(f32x4*)(ea_out + (size_t)e * EDIM + quad * 4) = y;
    }
}

// ---------------------------------------------------------------------------
extern "C" void kernel_launch(void* const* d_in, const int* in_sizes, int n_in,
                              void* d_out, int out_size, void* d_ws, size_t ws_size,
                              hipStream_t stream) {
    const float* s_in  = (const float*)d_in[0];     // [N][128] fp32
    const int*   ei    = (const int*)d_in[1];       // [2][E] int32
    const float* ea_in = (const float*)d_in[2];     // [E][16] fp32
    // d_in[3] = batch: dead
    const float* lnw = (const float*)d_in[4];
    const float* lnb = (const float*)d_in[5];
    const float* eW1 = (const float*)d_in[6];       // [5][272][16]
    const float* eb1 = (const float*)d_in[7];
    const float* eW2 = (const float*)d_in[8];       // [5][16][16]
    const float* eb2 = (const float*)d_in[9];
    // d_in[10..13]: dead (node MLP output discarded)

    float* out_s  = (float*)d_out;                          // [N][128]
    float* out_ea = (float*)d_out + (size_t)N_NODES * DIM;  // [E][16]

    ushort_t* w1s = (ushort_t*)d_ws;                     // 5*9*64*8 = 23040 elems
    ushort_t* w2s = w1s + (size_t)NLAYERS * 9 * 64 * 8;  // 5*64*8 = 2560 elems
    ushort_t* uv0 = w2s + (size_t)NLAYERS * 64 * 8;
    const size_t wWords  = (size_t)NLAYERS * 10 * 64 * 8;   // weight elems
    const size_t uvLayer = (size_t)N_NODES * EDIM;           // 1.6M elems
    const size_t needFused = (wWords + 2 * (size_t)NLAYERS * uvLayer) * 2;
    const int lnGrid = (N_NODES / 16 + 3) / 4;   // 1563
    // one 64-edge tile per block: 25000 blocks -> ~7 waves/SIMD occupancy
    // (the 4096-block grid-stride version ran at 30% occupancy, latency-bound
    //  on the random u/v gathers)
    const int eGrid = N_EDGES / 64;              // 25000

    swizzle_weights<<<13, 256, 0, stream>>>(eW1, eW2, w1s, w2s);

    if (ws_size >= needFused) {
        // u/v for ALL layers, laid out [node][NLAYERS][16]; single fused edge pass.
        ushort_t* u0 = uv0;
        ushort_t* v0 = u0 + (size_t)NLAYERS * uvLayer;
        ln_uv<<<lnGrid, 256, 0, stream>>>(s_in, out_s, lnw, lnb, w1s,
                                          u0, v0, 0, NLAYERS, NLAYERS);
        edge_fused<NLAYERS><<<eGrid, 256, 0, stream>>>(ea_in, out_ea, ei, u0, v0,
                                                       w1s, w2s, eb1, eb2, 0);
    } else {
        // Minimal ws: per-layer u/v slot ([node][1][16]), ea fp32 in-place in d_out.
        ushort_t* u0 = uv0;
        ushort_t* v0 = u0 + uvLayer;
        for (int l = 0; l < NLAYERS; ++l) {
            ln_uv<<<lnGrid, 256, 0, stream>>>(l == 0 ? s_in : out_s, out_s,
                                              lnw, lnb, w1s, u0, v0, l, l + 1, 1);
            edge_fused<1><<<eGrid, 256, 0, stream>>>(
                l == 0 ? ea_in : (const float*)out_ea, out_ea, ei, u0, v0,
                w1s, w2s, eb1, eb2, l);
        }
    }
}

// Round 7
// 434.898 us; speedup vs baseline: 1.0513x; 1.0513x over previous
//
#include <hip/hip_runtime.h>

// Problem constants (fixed by the reference)
#define N_NODES 100000
#define N_EDGES 1600000
#define DIM     128
#define EDIM    16
#define NLAYERS 5

typedef unsigned short ushort_t;
typedef short bf16x8 __attribute__((ext_vector_type(8)));   // 8 bf16 in 4 VGPRs
typedef float f32x4  __attribute__((ext_vector_type(4)));

__device__ __forceinline__ ushort_t f2bf(float f) {
    union { float f; unsigned int i; } c; c.f = f;
    unsigned int r = c.i + 0x7fffu + ((c.i >> 16) & 1u);   // RNE
    return (ushort_t)(r >> 16);
}
__device__ __forceinline__ float lo_bf(unsigned int w) {
    union { unsigned int i; float f; } c; c.i = w << 16; return c.f;
}
__device__ __forceinline__ float hi_bf(unsigned int w) {
    union { unsigned int i; float f; } c; c.i = w & 0xffff0000u; return c.f;
}
__device__ __forceinline__ unsigned int pk_bf16(float lo, float hi) {
    unsigned int r;
    asm("v_cvt_pk_bf16_f32 %0, %1, %2" : "=v"(r) : "v"(lo), "v"(hi));
    return r;
}
__device__ __forceinline__ bf16x8 pk8(f32x4 a, f32x4 b) {
    union { unsigned int w[4]; bf16x8 v; } c;
    c.w[0] = pk_bf16(a[0], a[1]); c.w[1] = pk_bf16(a[2], a[3]);
    c.w[2] = pk_bf16(b[0], b[1]); c.w[3] = pk_bf16(b[2], b[3]);
    return c.v;
}
// silu via fast hw reciprocal (~1ulp; noise vs bf16 rounding)
__device__ __forceinline__ float fast_silu(float x) {
    return x * __builtin_amdgcn_rcpf(1.0f + __expf(-x));
}
// Wave-local LDS ordering: drain ds ops + block compiler motion across.
// NOTE: only waits lgkmcnt -- outstanding GLOBAL loads issued earlier in
// program order (the next-tile prefetch) remain in flight across this.
__device__ __forceinline__ void lds_fence() {
    asm volatile("s_waitcnt lgkmcnt(0)" ::: "memory");
    __builtin_amdgcn_sched_barrier(0);
}

// ---------------------------------------------------------------------------
// Swizzle eW1 (272x16) / eW2 (16x16) per layer (fp32) into bf16 B-fragments.
// B[k][n]: lane = 16*quad + n holds k = quad*8 + j.
// B-fragment of M == A-fragment of M^T, so these buffers serve the
// transposed (operand-swapped) MFMAs below.
// w1s: [layer][t(0..8)][lane][8]; t0..3 = W1a, t4..7 = W1b, t8 = W1c (pad).
// w2s: [layer][lane][8]; K padded 16->32 (zeros).
// ---------------------------------------------------------------------------
__global__ void swizzle_weights(const float* __restrict__ eW1,
                                const float* __restrict__ eW2,
                                ushort_t* __restrict__ w1s,
                                ushort_t* __restrict__ w2s) {
    int id = blockIdx.x * 256 + threadIdx.x;
    if (id >= NLAYERS * 10 * 64) return;
    int lane = id & 63;
    int t10 = id >> 6;
    int layer = t10 / 10, t = t10 % 10;
    int n = lane & 15, quad = lane >> 4;
    if (t < 9) {
        ushort_t* dst = w1s + ((size_t)(layer * 9 + t) * 64 + lane) * 8;
        #pragma unroll
        for (int j = 0; j < 8; ++j) {
            int k = t * 32 + quad * 8 + j;
            dst[j] = (k < 2 * DIM + EDIM)
                       ? f2bf(eW1[((size_t)layer * 272 + k) * 16 + n])
                       : (ushort_t)0;
        }
    } else {
        ushort_t* dst = w2s + ((size_t)layer * 64 + lane) * 8;
        #pragma unroll
        for (int j = 0; j < 8; ++j) {
            int k = quad * 8 + j;
            dst[j] = (k < EDIM) ? f2bf(eW2[((size_t)layer * 16 + k) * 16 + n])
                                : (ushort_t)0;
        }
    }
}

// ---------------------------------------------------------------------------
// Fused LayerNorm chain + per-node projections (unchanged from R5).
// ---------------------------------------------------------------------------
__global__ __launch_bounds__(256) void ln_uv(
        const float* __restrict__ sin, float* __restrict__ sout,
        const float* __restrict__ lnw, const float* __restrict__ lnb, // [5][128]
        const ushort_t* __restrict__ w1s,                             // all layers
        ushort_t* __restrict__ u_buf, ushort_t* __restrict__ v_buf,
        int l0, int l1, int lstr) {
    const int wv = threadIdx.x >> 6, lane = threadIdx.x & 63;
    const int m = lane & 15, quad = lane >> 4;
    const int tile = blockIdx.x * 4 + wv;
    if (tile >= N_NODES / 16) return;           // 6250 tiles exactly
    const int node = tile * 16 + m;

    float x[32];
    {
        const float* row = sin + (size_t)node * DIM + quad * 8;
        #pragma unroll
        for (int t = 0; t < 4; ++t) {
            f32x4 a = *(const f32x4*)(row + t * 32);
            f32x4 b = *(const f32x4*)(row + t * 32 + 4);
            #pragma unroll
            for (int j = 0; j < 4; ++j) { x[t * 8 + j] = a[j]; x[t * 8 + 4 + j] = b[j]; }
        }
    }

    for (int li = l0; li < l1; ++li) {
        float s = 0.f;
        #pragma unroll
        for (int k = 0; k < 32; ++k) s += x[k];
        s += __shfl_xor(s, 16); s += __shfl_xor(s, 32);
        float mu = s * (1.0f / DIM);
        float ss = 0.f;
        #pragma unroll
        for (int k = 0; k < 32; ++k) { float d = x[k] - mu; ss += d * d; }
        ss += __shfl_xor(ss, 16); ss += __shfl_xor(ss, 32);
        float rs = rsqrtf(ss * (1.0f / DIM) + 1e-5f);

        const float* w = lnw + (size_t)li * DIM + quad * 8;
        const float* b = lnb + (size_t)li * DIM + quad * 8;
        f32x4 au = {0.f, 0.f, 0.f, 0.f}, av = {0.f, 0.f, 0.f, 0.f};
        #pragma unroll
        for (int t = 0; t < 4; ++t) {
            f32x4 wa = *(const f32x4*)(w + t * 32), wb = *(const f32x4*)(w + t * 32 + 4);
            f32x4 ba = *(const f32x4*)(b + t * 32), bb = *(const f32x4*)(b + t * 32 + 4);
            #pragma unroll
            for (int j = 0; j < 4; ++j) {
                x[t * 8 + j]     = (x[t * 8 + j]     - mu) * rs * wa[j] + ba[j];
                x[t * 8 + 4 + j] = (x[t * 8 + 4 + j] - mu) * rs * wb[j] + bb[j];
            }
            f32x4 ya, yb;
            #pragma unroll
            for (int j = 0; j < 4; ++j) { ya[j] = x[t * 8 + j]; yb[j] = x[t * 8 + 4 + j]; }
            bf16x8 af = pk8(ya, yb);
            bf16x8 bu = *(const bf16x8*)(w1s + ((size_t)(li * 9 + t)     * 64 + lane) * 8);
            bf16x8 bv = *(const bf16x8*)(w1s + ((size_t)(li * 9 + 4 + t) * 64 + lane) * 8);
            au = __builtin_amdgcn_mfma_f32_16x16x32_bf16(bu, af, au, 0, 0, 0);
            av = __builtin_amdgcn_mfma_f32_16x16x32_bf16(bv, af, av, 0, 0, 0);
        }
        size_t rec = ((size_t)node * lstr + (li - l0)) * EDIM + quad * 4;
        uint2 tu; tu.x = pk_bf16(au[0], au[1]); tu.y = pk_bf16(au[2], au[3]);
        uint2 tv; tv.x = pk_bf16(av[0], av[1]); tv.y = pk_bf16(av[2], av[3]);
        *(uint2*)(u_buf + rec) = tu;
        *(uint2*)(v_buf + rec) = tv;
    }

    float* orow = sout + (size_t)node * DIM + quad * 8;
    #pragma unroll
    for (int t = 0; t < 4; ++t) {
        f32x4 a, b;
        #pragma unroll
        for (int j = 0; j < 4; ++j) { a[j] = x[t * 8 + j]; b[j] = x[t * 8 + 4 + j]; }
        *(f32x4*)(orow + t * 32) = a;
        *(f32x4*)(orow + t * 32 + 4) = b;
    }
}

// ---------------------------------------------------------------------------
// FUSED edge pass, SOFTWARE-PIPELINED (T14 async-stage split):
// per grid-stride iteration, issue tile t+1's u/v gathers + ea load and
// tile t+2's ei load BEFORE computing tile t. The random-gather latency
// (~600-900cy) hides under the ~1500cy 5-layer compute. The per-layer
// lgkmcnt fences only drain LDS counters, so the prefetch loads stay in
// flight across them.
// Transposed orientation + per-wave LDS transpose as in R5 (best measured).
// In-place safe: tiles partition edges; prefetch reads are from different
// tiles than the current store; each edge read/written by its own wave.
// ---------------------------------------------------------------------------
template<int NL>
__global__ __launch_bounds__(256) void edge_fused(
        const float* __restrict__ ea_in, float* __restrict__ ea_out,
        const int* __restrict__ ei,
        const ushort_t* __restrict__ u_buf, const ushort_t* __restrict__ v_buf,
        const ushort_t* __restrict__ w1s, const ushort_t* __restrict__ w2s,
        const float* __restrict__ eb1, const float* __restrict__ eb2,
        int l0) {
    __shared__ ushort_t tbH[4][16 * 24];   // per-wave, 48B rows (16B-aligned reads)
    __shared__ ushort_t tbY[4][16 * 24];
    const int wv = threadIdx.x >> 6, lane = threadIdx.x & 63;
    const int m = lane & 15, quad = lane >> 4;

    bf16x8 w1f[NL], w2f[NL];
    f32x4 b1[NL], b2[NL];
    #pragma unroll
    for (int l = 0; l < NL; ++l) {
        w1f[l] = *(const bf16x8*)(w1s + (((size_t)(l0 + l) * 9 + 8) * 64 + lane) * 8);
        w2f[l] = *(const bf16x8*)(w2s + ((size_t)(l0 + l) * 64 + lane) * 8);
        #pragma unroll
        for (int r = 0; r < 4; ++r) {
            b1[l][r] = eb1[(l0 + l) * EDIM + quad * 4 + r];
            b2[l][r] = eb2[(l0 + l) * EDIM + quad * 4 + r];
        }
    }
    ushort_t* tlH = tbH[wv];
    ushort_t* tlY = tbY[wv];
    const bf16x8 zf = {0, 0, 0, 0, 0, 0, 0, 0};
    const f32x4 z4 = {0.f, 0.f, 0.f, 0.f};
    const int nTiles = N_EDGES / 64;
    const int stride = gridDim.x;

    int tile = blockIdx.x;
    if (tile >= nTiles) return;

    // ---- prologue: tile0 state (gathers + ea in flight), tile1 ei in flight
    uint2 gu[NL], gv[NL];
    f32x4 ea_a = z4, ea_b = z4;
    int es_n, ed_n;
    {
        const int e0 = tile * 64 + wv * 16 + m;
        const int es = ei[e0];
        const int ed = ei[N_EDGES + e0];
        #pragma unroll
        for (int l = 0; l < NL; ++l) {
            gu[l] = *(const uint2*)(u_buf + ((size_t)es * NL + l) * EDIM + quad * 4);
            gv[l] = *(const uint2*)(v_buf + ((size_t)ed * NL + l) * EDIM + quad * 4);
        }
        if (quad < 2) {
            const float* ep = ea_in + (size_t)e0 * EDIM + quad * 8;
            ea_a = *(const f32x4*)ep; ea_b = *(const f32x4*)(ep + 4);
        }
        const int t1 = tile + stride;
        const int e1 = (t1 < nTiles ? t1 : tile) * 64 + wv * 16 + m;
        es_n = ei[e1];
        ed_n = ei[N_EDGES + e1];
    }

    for (; tile < nTiles; tile += stride) {
        const int tn = tile + stride;
        const bool hn = tn < nTiles;
        const int tc = hn ? tn : tile;          // clamped next tile

        // ---- issue NEXT tile's gathers + ea (stay in flight through compute)
        uint2 gun[NL], gvn[NL];
        #pragma unroll
        for (int l = 0; l < NL; ++l) {
            gun[l] = *(const uint2*)(u_buf + ((size_t)es_n * NL + l) * EDIM + quad * 4);
            gvn[l] = *(const uint2*)(v_buf + ((size_t)ed_n * NL + l) * EDIM + quad * 4);
        }
        f32x4 ean_a = z4, ean_b = z4;
        {
            const int en = tc * 64 + wv * 16 + m;
            if (quad < 2) {
                const float* ep = ea_in + (size_t)en * EDIM + quad * 8;
                ean_a = *(const f32x4*)ep; ean_b = *(const f32x4*)(ep + 4);
            }
        }
        // ---- issue tile+2's ei
        int es_nn, ed_nn;
        {
            const int t2 = tn + stride;
            const int e2 = (t2 < nTiles ? t2 : tc) * 64 + wv * 16 + m;
            es_nn = ei[e2];
            ed_nn = ei[N_EDGES + e2];
        }

        // ---- compute CURRENT tile
        bf16x8 af = zf;
        if (quad < 2) af = pk8(ea_a, ea_b);

        f32x4 y = z4;
        #pragma unroll
        for (int l = 0; l < NL; ++l) {
            f32x4 acc = z4;
            acc = __builtin_amdgcn_mfma_f32_16x16x32_bf16(w1f[l], af, acc, 0, 0, 0);
            float x0 = acc[0] + lo_bf(gu[l].x) + lo_bf(gv[l].x) + b1[l][0];
            float x1 = acc[1] + hi_bf(gu[l].x) + hi_bf(gv[l].x) + b1[l][1];
            float x2 = acc[2] + lo_bf(gu[l].y) + lo_bf(gv[l].y) + b1[l][2];
            float x3 = acc[3] + hi_bf(gu[l].y) + hi_bf(gv[l].y) + b1[l][3];
            float h0 = fast_silu(x0);
            float h1 = fast_silu(x1);
            float h2 = fast_silu(x2);
            float h3 = fast_silu(x3);

            // transpose h^T (C layout) -> B-frag via per-wave LDS
            uint2 hw; hw.x = pk_bf16(h0, h1); hw.y = pk_bf16(h2, h3);
            *(uint2*)(tlH + m * 24 + quad * 4) = hw;
            lds_fence();
            bf16x8 hf = zf;
            if (quad < 2) hf = *(const bf16x8*)(tlH + m * 24 + quad * 8);

            f32x4 acc2 = z4;
            acc2 = __builtin_amdgcn_mfma_f32_16x16x32_bf16(w2f[l], hf, acc2, 0, 0, 0);
            y[0] = acc2[0] + b2[l][0];
            y[1] = acc2[1] + b2[l][1];
            y[2] = acc2[2] + b2[l][2];
            y[3] = acc2[3] + b2[l][3];

            if (l < NL - 1) {
                uint2 yw; yw.x = pk_bf16(y[0], y[1]); yw.y = pk_bf16(y[2], y[3]);
                *(uint2*)(tlY + m * 24 + quad * 4) = yw;
                lds_fence();
                af = zf;
                if (quad < 2) af = *(const bf16x8*)(tlY + m * 24 + quad * 8);
            }
        }
        // store ea'[edge m][4q..4q+3] : contiguous 16B per lane
        const int e = tile * 64 + wv * 16 + m;
        *(f32x4*)(ea_out + (size_t)e * EDIM + quad * 4) = y;

        // ---- rotate pipeline state
        #pragma unroll
        for (int l = 0; l < NL; ++l) { gu[l] = gun[l]; gv[l] = gvn[l]; }
        ea_a = ean_a; ea_b = ean_b;
        es_n = es_nn; ed_n = ed_nn;
    }
}

// ---------------------------------------------------------------------------
extern "C" void kernel_launch(void* const* d_in, const int* in_sizes, int n_in,
                              void* d_out, int out_size, void* d_ws, size_t ws_size,
                              hipStream_t stream) {
    const float* s_in  = (const float*)d_in[0];     // [N][128] fp32
    const int*   ei    = (const int*)d_in[1];       // [2][E] int32
    const float* ea_in = (const float*)d_in[2];     // [E][16] fp32
    // d_in[3] = batch: dead
    const float* lnw = (const float*)d_in[4];
    const float* lnb = (const float*)d_in[5];
    const float* eW1 = (const float*)d_in[6];       // [5][272][16]
    const float* eb1 = (const float*)d_in[7];
    const float* eW2 = (const float*)d_in[8];       // [5][16][16]
    const float* eb2 = (const float*)d_in[9];
    // d_in[10..13]: dead (node MLP output discarded)

    float* out_s  = (float*)d_out;                          // [N][128]
    float* out_ea = (float*)d_out + (size_t)N_NODES * DIM;  // [E][16]

    ushort_t* w1s = (ushort_t*)d_ws;                     // 5*9*64*8 = 23040 elems
    ushort_t* w2s = w1s + (size_t)NLAYERS * 9 * 64 * 8;  // 5*64*8 = 2560 elems
    ushort_t* uv0 = w2s + (size_t)NLAYERS * 64 * 8;
    const size_t wWords  = (size_t)NLAYERS * 10 * 64 * 8;   // weight elems
    const size_t uvLayer = (size_t)N_NODES * EDIM;           // 1.6M elems
    const size_t needFused = (wWords + 2 * (size_t)NLAYERS * uvLayer) * 2;
    const int lnGrid = (N_NODES / 16 + 3) / 4;   // 1563
    // 4096 blocks x ~6 tiles: amortizes the weight-fragment prologue and
    // feeds the 1-deep software pipeline (25000 one-tile blocks regressed).
    const int eGrid = 4096;

    swizzle_weights<<<13, 256, 0, stream>>>(eW1, eW2, w1s, w2s);

    if (ws_size >= needFused) {
        // u/v for ALL layers, laid out [node][NLAYERS][16]; single fused edge pass.
        ushort_t* u0 = uv0;
        ushort_t* v0 = u0 + (size_t)NLAYERS * uvLayer;
        ln_uv<<<lnGrid, 256, 0, stream>>>(s_in, out_s, lnw, lnb, w1s,
                                          u0, v0, 0, NLAYERS, NLAYERS);
        edge_fused<NLAYERS><<<eGrid, 256, 0, stream>>>(ea_in, out_ea, ei, u0, v0,
                                                       w1s, w2s, eb1, eb2, 0);
    } else {
        // Minimal ws: per-layer u/v slot ([node][1][16]), ea fp32 in-place in d_out.
        ushort_t* u0 = uv0;
        ushort_t* v0 = u0 + uvLayer;
        for (int l = 0; l < NLAYERS; ++l) {
            ln_uv<<<lnGrid, 256, 0, stream>>>(l == 0 ? s_in : out_s, out_s,
                                              lnw, lnb, w1s, u0, v0, l, l + 1, 1);
            edge_fused<1><<<eGrid, 256, 0, stream>>>(
                l == 0 ? ea_in : (const float*)out_ea, out_ea, ei, u0, v0,
                w1s, w2s, eb1, eb2, l);
        }
    }
}

// Round 14
// 431.309 us; speedup vs baseline: 1.0601x; 1.0083x over previous
//
#include <hip/hip_runtime.h>

// Problem constants (fixed by the reference)
#define N_NODES 100000
#define N_EDGES 1600000
#define DIM     128
#define EDIM    16
#define NLAYERS 5

typedef unsigned short ushort_t;
typedef short bf16x8 __attribute__((ext_vector_type(8)));   // 8 bf16 in 4 VGPRs
typedef float f32x4  __attribute__((ext_vector_type(4)));

__device__ __forceinline__ ushort_t f2bf(float f) {
    union { float f; unsigned int i; } c; c.f = f;
    unsigned int r = c.i + 0x7fffu + ((c.i >> 16) & 1u);   // RNE
    return (ushort_t)(r >> 16);
}
__device__ __forceinline__ float lo_bf(unsigned int w) {
    union { unsigned int i; float f; } c; c.i = w << 16; return c.f;
}
__device__ __forceinline__ float hi_bf(unsigned int w) {
    union { unsigned int i; float f; } c; c.i = w & 0xffff0000u; return c.f;
}
__device__ __forceinline__ unsigned int pk_bf16(float lo, float hi) {
    unsigned int r;
    asm("v_cvt_pk_bf16_f32 %0, %1, %2" : "=v"(r) : "v"(lo), "v"(hi));
    return r;
}
__device__ __forceinline__ bf16x8 pk8(f32x4 a, f32x4 b) {
    union { unsigned int w[4]; bf16x8 v; } c;
    c.w[0] = pk_bf16(a[0], a[1]); c.w[1] = pk_bf16(a[2], a[3]);
    c.w[2] = pk_bf16(b[0], b[1]); c.w[3] = pk_bf16(b[2], b[3]);
    return c.v;
}
// silu via fast hw reciprocal (~1ulp; noise vs bf16 rounding)
__device__ __forceinline__ float fast_silu(float x) {
    return x * __builtin_amdgcn_rcpf(1.0f + __expf(-x));
}
// Wave-local LDS ordering: drain ds ops + block compiler motion across.
// Only waits lgkmcnt -- outstanding GLOBAL loads issued earlier in program
// order (the next-tile prefetch) remain in flight across this.
__device__ __forceinline__ void lds_fence() {
    asm volatile("s_waitcnt lgkmcnt(0)" ::: "memory");
    __builtin_amdgcn_sched_barrier(0);
}

// ---------------------------------------------------------------------------
// Swizzle weights into bf16 B-fragments (B-frag of M == A-frag of M^T).
// w1s: [layer][t(0..8)][lane][8]; t0..3 = W1a, t4..7 = W1b, t8 = W1c (pad).
// w2s: [layer][lane][8]; K padded 16->32 (zeros).
// Composite weights to shorten the edge chain. Between ea'_l = W2_l^T h
// and x_{l+1} = W1c_{l+1}^T ea' there is no nonlinearity, so:
//   Wc_{l+1} = W2_l @ W1c_{l+1}   (16x16, computed fp32 -> bf16 frag)
//   bc_{l+1} = W1c_{l+1}^T b2_l + b1_{l+1}   (fp32)
// wcs: [4][lane][8] frags for global layers 1..4; bcs: [4][16] fp32.
// ---------------------------------------------------------------------------
__global__ void swizzle_weights(const float* __restrict__ eW1,
                                const float* __restrict__ eW2,
                                const float* __restrict__ eb1,
                                const float* __restrict__ eb2,
                                ushort_t* __restrict__ w1s,
                                ushort_t* __restrict__ w2s,
                                ushort_t* __restrict__ wcs,
                                float* __restrict__ bcs) {
    int id = blockIdx.x * 256 + threadIdx.x;
    const int base = NLAYERS * 10 * 64;
    if (id < base) {
        int lane = id & 63;
        int t10 = id >> 6;
        int layer = t10 / 10, t = t10 % 10;
        int n = lane & 15, quad = lane >> 4;
        if (t < 9) {
            ushort_t* dst = w1s + ((size_t)(layer * 9 + t) * 64 + lane) * 8;
            #pragma unroll
            for (int j = 0; j < 8; ++j) {
                int k = t * 32 + quad * 8 + j;
                dst[j] = (k < 2 * DIM + EDIM)
                           ? f2bf(eW1[((size_t)layer * 272 + k) * 16 + n])
                           : (ushort_t)0;
            }
        } else {
            ushort_t* dst = w2s + ((size_t)layer * 64 + lane) * 8;
            #pragma unroll
            for (int j = 0; j < 8; ++j) {
                int k = quad * 8 + j;
                dst[j] = (k < EDIM) ? f2bf(eW2[((size_t)layer * 16 + k) * 16 + n])
                                    : (ushort_t)0;
            }
        }
    } else if (id < base + 4 * 64) {            // composite weight frags
        int id2 = id - base;
        int l = id2 >> 6;                       // 0..3 -> global layer l+1
        int lane = id2 & 63, n = lane & 15, quad = lane >> 4;
        ushort_t* dst = wcs + ((size_t)l * 64 + lane) * 8;
        #pragma unroll
        for (int j = 0; j < 8; ++j) {
            int r = quad * 8 + j;               // h-feature (contraction) index
            float acc = 0.f;
            if (r < EDIM)
                for (int k = 0; k < EDIM; ++k)
                    acc += eW2[((size_t)l * 16 + r) * 16 + k]
                         * eW1[((size_t)(l + 1) * 272 + 256 + k) * 16 + n];
            dst[j] = (r < EDIM) ? f2bf(acc) : (ushort_t)0;
        }
    } else if (id < base + 4 * 64 + 64) {       // composite biases
        int id2 = id - base - 4 * 64;           // 0..63
        int l = id2 >> 4, n = id2 & 15;         // global layer l+1
        float acc = eb1[(l + 1) * 16 + n];
        for (int k = 0; k < EDIM; ++k)
            acc += eb2[l * 16 + k] * eW1[((size_t)(l + 1) * 272 + 256 + k) * 16 + n];
        bcs[l * 16 + n] = acc;
    }
}

// ---------------------------------------------------------------------------
// Fused LayerNorm chain + per-node projections (unchanged from R5).
// ---------------------------------------------------------------------------
__global__ __launch_bounds__(256) void ln_uv(
        const float* __restrict__ sin, float* __restrict__ sout,
        const float* __restrict__ lnw, const float* __restrict__ lnb, // [5][128]
        const ushort_t* __restrict__ w1s,                             // all layers
        ushort_t* __restrict__ u_buf, ushort_t* __restrict__ v_buf,
        int l0, int l1, int lstr) {
    const int wv = threadIdx.x >> 6, lane = threadIdx.x & 63;
    const int m = lane & 15, quad = lane >> 4;
    const int tile = blockIdx.x * 4 + wv;
    if (tile >= N_NODES / 16) return;           // 6250 tiles exactly
    const int node = tile * 16 + m;

    float x[32];
    {
        const float* row = sin + (size_t)node * DIM + quad * 8;
        #pragma unroll
        for (int t = 0; t < 4; ++t) {
            f32x4 a = *(const f32x4*)(row + t * 32);
            f32x4 b = *(const f32x4*)(row + t * 32 + 4);
            #pragma unroll
            for (int j = 0; j < 4; ++j) { x[t * 8 + j] = a[j]; x[t * 8 + 4 + j] = b[j]; }
        }
    }

    for (int li = l0; li < l1; ++li) {
        float s = 0.f;
        #pragma unroll
        for (int k = 0; k < 32; ++k) s += x[k];
        s += __shfl_xor(s, 16); s += __shfl_xor(s, 32);
        float mu = s * (1.0f / DIM);
        float ss = 0.f;
        #pragma unroll
        for (int k = 0; k < 32; ++k) { float d = x[k] - mu; ss += d * d; }
        ss += __shfl_xor(ss, 16); ss += __shfl_xor(ss, 32);
        float rs = rsqrtf(ss * (1.0f / DIM) + 1e-5f);

        const float* w = lnw + (size_t)li * DIM + quad * 8;
        const float* b = lnb + (size_t)li * DIM + quad * 8;
        f32x4 au = {0.f, 0.f, 0.f, 0.f}, av = {0.f, 0.f, 0.f, 0.f};
        #pragma unroll
        for (int t = 0; t < 4; ++t) {
            f32x4 wa = *(const f32x4*)(w + t * 32), wb = *(const f32x4*)(w + t * 32 + 4);
            f32x4 ba = *(const f32x4*)(b + t * 32), bb = *(const f32x4*)(b + t * 32 + 4);
            #pragma unroll
            for (int j = 0; j < 4; ++j) {
                x[t * 8 + j]     = (x[t * 8 + j]     - mu) * rs * wa[j] + ba[j];
                x[t * 8 + 4 + j] = (x[t * 8 + 4 + j] - mu) * rs * wb[j] + bb[j];
            }
            f32x4 ya, yb;
            #pragma unroll
            for (int j = 0; j < 4; ++j) { ya[j] = x[t * 8 + j]; yb[j] = x[t * 8 + 4 + j]; }
            bf16x8 af = pk8(ya, yb);
            bf16x8 bu = *(const bf16x8*)(w1s + ((size_t)(li * 9 + t)     * 64 + lane) * 8);
            bf16x8 bv = *(const bf16x8*)(w1s + ((size_t)(li * 9 + 4 + t) * 64 + lane) * 8);
            au = __builtin_amdgcn_mfma_f32_16x16x32_bf16(bu, af, au, 0, 0, 0);
            av = __builtin_amdgcn_mfma_f32_16x16x32_bf16(bv, af, av, 0, 0, 0);
        }
        size_t rec = ((size_t)node * lstr + (li - l0)) * EDIM + quad * 4;
        uint2 tu; tu.x = pk_bf16(au[0], au[1]); tu.y = pk_bf16(au[2], au[3]);
        uint2 tv; tv.x = pk_bf16(av[0], av[1]); tv.y = pk_bf16(av[2], av[3]);
        *(uint2*)(u_buf + rec) = tu;
        *(uint2*)(v_buf + rec) = tv;
    }

    float* orow = sout + (size_t)node * DIM + quad * 8;
    #pragma unroll
    for (int t = 0; t < 4; ++t) {
        f32x4 a, b;
        #pragma unroll
        for (int j = 0; j < 4; ++j) { a[j] = x[t * 8 + j]; b[j] = x[t * 8 + 4 + j]; }
        *(f32x4*)(orow + t * 32) = a;
        *(f32x4*)(orow + t * 32 + 4) = b;
    }
}

// ---------------------------------------------------------------------------
// FUSED edge pass with COMPOSED weights: per tile the chain is now
//   x_0 = W1c_0^T ea + u0+v0+b1_0 ;  h_0 = silu(x_0)
//   for l=1..NL-1:  x_l = Wc_l^T h_{l-1} + u_l+v_l+bc_l ;  h_l = silu(x_l)
//   ea_out = W2_{NL-1}^T h_{NL-1} + b2
// => ONE LDS transpose + ONE MFMA per layer (was two of each): 5 fences,
// 6 MFMAs per tile instead of 9/10. Software pipeline (R7) retained:
// next tile's u/v gathers + ea and tile+2's ei are issued before compute;
// they stay in flight across the lgkm-only fences.
// In-place safe: tiles partition edges; each edge read/written by its wave.
// ---------------------------------------------------------------------------
template<int NL>
__global__ __launch_bounds__(256) void edge_fused(
        const float* __restrict__ ea_in, float* __restrict__ ea_out,
        const int* __restrict__ ei,
        const ushort_t* __restrict__ u_buf, const ushort_t* __restrict__ v_buf,
        const ushort_t* __restrict__ w1s, const ushort_t* __restrict__ w2s,
        const ushort_t* __restrict__ wcs, const float* __restrict__ bcs,
        const float* __restrict__ eb1, const float* __restrict__ eb2,
        int l0) {
    __shared__ ushort_t tbH[4][16 * 24];   // per-wave, 48B rows (16B-aligned reads)
    const int wv = threadIdx.x >> 6, lane = threadIdx.x & 63;
    const int m = lane & 15, quad = lane >> 4;

    // weight fragments: layer-0 W1c, composite Wc for l=1..NL-1, final W2
    const bf16x8 w1f0 = *(const bf16x8*)(w1s + (((size_t)l0 * 9 + 8) * 64 + lane) * 8);
    const bf16x8 w2f  = *(const bf16x8*)(w2s + ((size_t)(l0 + NL - 1) * 64 + lane) * 8);
    bf16x8 wcf[NL > 1 ? NL - 1 : 1];
    #pragma unroll
    for (int l = 1; l < NL; ++l)
        wcf[l - 1] = *(const bf16x8*)(wcs + ((size_t)(l0 + l - 1) * 64 + lane) * 8);
    f32x4 bx[NL], b2v;
    #pragma unroll
    for (int r = 0; r < 4; ++r) {
        bx[0][r] = eb1[l0 * EDIM + quad * 4 + r];
        b2v[r]   = eb2[(l0 + NL - 1) * EDIM + quad * 4 + r];
    }
    #pragma unroll
    for (int l = 1; l < NL; ++l)
        #pragma unroll
        for (int r = 0; r < 4; ++r)
            bx[l][r] = bcs[(l0 + l - 1) * EDIM + quad * 4 + r];

    ushort_t* tlH = tbH[wv];
    const bf16x8 zf = {0, 0, 0, 0, 0, 0, 0, 0};
    const f32x4 z4 = {0.f, 0.f, 0.f, 0.f};
    const int nTiles = N_EDGES / 64;
    const int stride = gridDim.x;

    int tile = blockIdx.x;
    if (tile >= nTiles) return;

    // ---- prologue: tile0 state (gathers + ea in flight), tile1 ei in flight
    uint2 gu[NL], gv[NL];
    f32x4 ea_a = z4, ea_b = z4;
    int es_n, ed_n;
    {
        const int e0 = tile * 64 + wv * 16 + m;
        const int es = ei[e0];
        const int ed = ei[N_EDGES + e0];
        #pragma unroll
        for (int l = 0; l < NL; ++l) {
            gu[l] = *(const uint2*)(u_buf + ((size_t)es * NL + l) * EDIM + quad * 4);
            gv[l] = *(const uint2*)(v_buf + ((size_t)ed * NL + l) * EDIM + quad * 4);
        }
        if (quad < 2) {
            const float* ep = ea_in + (size_t)e0 * EDIM + quad * 8;
            ea_a = *(const f32x4*)ep; ea_b = *(const f32x4*)(ep + 4);
        }
        const int t1 = tile + stride;
        const int e1 = (t1 < nTiles ? t1 : tile) * 64 + wv * 16 + m;
        es_n = ei[e1];
        ed_n = ei[N_EDGES + e1];
    }

    for (; tile < nTiles; tile += stride) {
        const int tn = tile + stride;
        const bool hn = tn < nTiles;
        const int tc = hn ? tn : tile;          // clamped next tile

        // ---- issue NEXT tile's gathers + ea (stay in flight through compute)
        uint2 gun[NL], gvn[NL];
        #pragma unroll
        for (int l = 0; l < NL; ++l) {
            gun[l] = *(const uint2*)(u_buf + ((size_t)es_n * NL + l) * EDIM + quad * 4);
            gvn[l] = *(const uint2*)(v_buf + ((size_t)ed_n * NL + l) * EDIM + quad * 4);
        }
        f32x4 ean_a = z4, ean_b = z4;
        {
            const int en = tc * 64 + wv * 16 + m;
            if (quad < 2) {
                const float* ep = ea_in + (size_t)en * EDIM + quad * 8;
                ean_a = *(const f32x4*)ep; ean_b = *(const f32x4*)(ep + 4);
            }
        }
        // ---- issue tile+2's ei
        int es_nn, ed_nn;
        {
            const int t2 = tn + stride;
            const int e2 = (t2 < nTiles ? t2 : tc) * 64 + wv * 16 + m;
            es_nn = ei[e2];
            ed_nn = ei[N_EDGES + e2];
        }

        // ---- compute CURRENT tile
        f32x4 hv;   // h in C layout: lane(quad,m) = h[edge m][feat quad*4+r]
        {
            bf16x8 af = zf;
            if (quad < 2) af = pk8(ea_a, ea_b);
            f32x4 acc = __builtin_amdgcn_mfma_f32_16x16x32_bf16(w1f0, af, z4, 0, 0, 0);
            hv[0] = fast_silu(acc[0] + lo_bf(gu[0].x) + lo_bf(gv[0].x) + bx[0][0]);
            hv[1] = fast_silu(acc[1] + hi_bf(gu[0].x) + hi_bf(gv[0].x) + bx[0][1]);
            hv[2] = fast_silu(acc[2] + lo_bf(gu[0].y) + lo_bf(gv[0].y) + bx[0][2]);
            hv[3] = fast_silu(acc[3] + hi_bf(gu[0].y) + hi_bf(gv[0].y) + bx[0][3]);
        }
        #pragma unroll
        for (int l = 1; l < NL; ++l) {
            // transpose h (C layout) -> B-frag via per-wave LDS
            uint2 hw; hw.x = pk_bf16(hv[0], hv[1]); hw.y = pk_bf16(hv[2], hv[3]);
            *(uint2*)(tlH + m * 24 + quad * 4) = hw;
            lds_fence();
            bf16x8 hf = zf;
            if (quad < 2) hf = *(const bf16x8*)(tlH + m * 24 + quad * 8);

            f32x4 acc = __builtin_amdgcn_mfma_f32_16x16x32_bf16(wcf[l - 1], hf, z4, 0, 0, 0);
            hv[0] = fast_silu(acc[0] + lo_bf(gu[l].x) + lo_bf(gv[l].x) + bx[l][0]);
            hv[1] = fast_silu(acc[1] + hi_bf(gu[l].x) + hi_bf(gv[l].x) + bx[l][1]);
            hv[2] = fast_silu(acc[2] + lo_bf(gu[l].y) + lo_bf(gv[l].y) + bx[l][2]);
            hv[3] = fast_silu(acc[3] + hi_bf(gu[l].y) + hi_bf(gv[l].y) + bx[l][3]);
        }
        // final: ea_out = W2^T h + b2
        f32x4 y;
        {
            uint2 hw; hw.x = pk_bf16(hv[0], hv[1]); hw.y = pk_bf16(hv[2], hv[3]);
            *(uint2*)(tlH + m * 24 + quad * 4) = hw;
            lds_fence();
            bf16x8 hf = zf;
            if (quad < 2) hf = *(const bf16x8*)(tlH + m * 24 + quad * 8);
            f32x4 acc2 = __builtin_amdgcn_mfma_f32_16x16x32_bf16(w2f, hf, z4, 0, 0, 0);
            y[0] = acc2[0] + b2v[0];
            y[1] = acc2[1] + b2v[1];
            y[2] = acc2[2] + b2v[2];
            y[3] = acc2[3] + b2v[3];
        }
        const int e = tile * 64 + wv * 16 + m;
        *(f32x4*)(ea_out + (size_t)e * EDIM + quad * 4) = y;

        // ---- rotate pipeline state
        #pragma unroll
        for (int l = 0; l < NL; ++l) { gu[l] = gun[l]; gv[l] = gvn[l]; }
        ea_a = ean_a; ea_b = ean_b;
        es_n = es_nn; ed_n = ed_nn;
    }
}

// ---------------------------------------------------------------------------
extern "C" void kernel_launch(void* const* d_in, const int* in_sizes, int n_in,
                              void* d_out, int out_size, void* d_ws, size_t ws_size,
                              hipStream_t stream) {
    const float* s_in  = (const float*)d_in[0];     // [N][128] fp32
    const int*   ei    = (const int*)d_in[1];       // [2][E] int32
    const float* ea_in = (const float*)d_in[2];     // [E][16] fp32
    // d_in[3] = batch: dead
    const float* lnw = (const float*)d_in[4];
    const float* lnb = (const float*)d_in[5];
    const float* eW1 = (const float*)d_in[6];       // [5][272][16]
    const float* eb1 = (const float*)d_in[7];
    const float* eW2 = (const float*)d_in[8];       // [5][16][16]
    const float* eb2 = (const float*)d_in[9];
    // d_in[10..13]: dead (node MLP output discarded)

    float* out_s  = (float*)d_out;                          // [N][128]
    float* out_ea = (float*)d_out + (size_t)N_NODES * DIM;  // [E][16]

    ushort_t* w1s = (ushort_t*)d_ws;                     // 5*9*64*8 = 23040 elems
    ushort_t* w2s = w1s + (size_t)NLAYERS * 9 * 64 * 8;  // 5*64*8 = 2560 elems
    ushort_t* wcs = w2s + (size_t)NLAYERS * 64 * 8;      // 4*64*8 = 2048 elems
    float*    bcs = (float*)(wcs + 4 * 64 * 8);          // 64 floats = 128 elems
    ushort_t* uv0 = wcs + 4 * 64 * 8 + 128;
    const size_t wWords  = (size_t)NLAYERS * 10 * 64 * 8 + 4 * 64 * 8 + 128;
    const size_t uvLayer = (size_t)N_NODES * EDIM;           // 1.6M elems
    const size_t needFused = (wWords + 2 * (size_t)NLAYERS * uvLayer) * 2;
    const int lnGrid = (N_NODES / 16 + 3) / 4;   // 1563
    // 4096 blocks x ~6 tiles: amortizes the weight prologue and feeds the
    // 1-deep software pipeline.
    const int eGrid = 4096;

    swizzle_weights<<<14, 256, 0, stream>>>(eW1, eW2, eb1, eb2, w1s, w2s, wcs, bcs);

    if (ws_size >= needFused) {
        // u/v for ALL layers, laid out [node][NLAYERS][16]; single fused edge pass.
        ushort_t* u0 = uv0;
        ushort_t* v0 = u0 + (size_t)NLAYERS * uvLayer;
        ln_uv<<<lnGrid, 256, 0, stream>>>(s_in, out_s, lnw, lnb, w1s,
                                          u0, v0, 0, NLAYERS, NLAYERS);
        edge_fused<NLAYERS><<<eGrid, 256, 0, stream>>>(ea_in, out_ea, ei, u0, v0,
                                                       w1s, w2s, wcs, bcs,
                                                       eb1, eb2, 0);
    } else {
        // Minimal ws: per-layer u/v slot ([node][1][16]), ea fp32 in-place.
        // NL=1 never touches wcs/bcs (no composite layers).
        ushort_t* u0 = uv0;
        ushort_t* v0 = u0 + uvLayer;
        for (int l = 0; l < NLAYERS; ++l) {
            ln_uv<<<lnGrid, 256, 0, stream>>>(l == 0 ? s_in : out_s, out_s,
                                              lnw, lnb, w1s, u0, v0, l, l + 1, 1);
            edge_fused<1><<<eGrid, 256, 0, stream>>>(
                l == 0 ? ea_in : (const float*)out_ea, out_ea, ei, u0, v0,
                w1s, w2s, wcs, bcs, eb1, eb2, l);
        }
    }
}